// Round 1
// baseline (299.378 us; speedup 1.0000x reference)
//
#include <hip/hip_runtime.h>
#include <hip/hip_bf16.h>
#include <math.h>
#include <stdint.h>

typedef __bf16 bf16;
typedef __bf16 bf16x8 __attribute__((ext_vector_type(8)));
typedef __bf16 bf16x4 __attribute__((ext_vector_type(4)));
typedef float  f32x4  __attribute__((ext_vector_type(4)));

#define MFMA16(a,b,c) __builtin_amdgcn_mfma_f32_16x16x32_bf16((a),(b),(c),0,0,0)
#define GLOAD_LDS16(g, l) \
  __builtin_amdgcn_global_load_lds((__attribute__((address_space(1))) void*)(g), \
                                   (__attribute__((address_space(3))) void*)(l), 16, 0, 0)

static constexpr int kB  = 2;
static constexpr int kS  = 2048;
static constexpr int kD  = 1024;
static constexpr int kH  = 16;
static constexpr int kHD = 64;
static constexpr int kM  = kB * kS;         // 4096
static constexpr float kScale = 0.125f;     // 1/sqrt(64)

// ---------------- fp32 -> bf16 conversion (x + 4 weights) ----------------
__global__ void cvt_all(const float* __restrict__ x,
                        const float* __restrict__ wq, const float* __restrict__ wk,
                        const float* __restrict__ wv, const float* __restrict__ wo,
                        bf16* __restrict__ xb,
                        bf16* __restrict__ wqb, bf16* __restrict__ wkb,
                        bf16* __restrict__ wvb, bf16* __restrict__ wob)
{
  const int i = blockIdx.x * 256 + threadIdx.x;   // float4 index
  const int NX4 = (kM * kD) / 4;                  // 1048576
  const int NW4 = (kD * kD) / 4;                  // 262144 = 2^18
  const float* src; bf16* dst; int off;
  if (i < NX4) { src = x; dst = xb; off = i; }
  else {
    const int j = i - NX4;
    const int seg = j >> 18;
    off = j & (NW4 - 1);
    src = (seg == 0) ? wq : (seg == 1) ? wk : (seg == 2) ? wv : wo;
    dst = (seg == 0) ? wqb : (seg == 1) ? wkb : (seg == 2) ? wvb : wob;
  }
  const float4 v = ((const float4*)src)[off];
  bf16x4 o = { (bf16)v.x, (bf16)v.y, (bf16)v.z, (bf16)v.w };
  ((bf16x4*)dst)[off] = o;
}

// ---------------- 128x128 tile bf16 GEMM core (C = A * B^T) ----------------
// A: [M,K] bf16 row-major. Bw: [N,K] bf16 row-major. BK=32, 256 threads, 2x2 waves.
__device__ __forceinline__ void gemm_core_128(
    const bf16* __restrict__ A, const bf16* __restrict__ Bw,
    int m0, int n0, int K, bf16* aT, bf16* bT, f32x4 acc[4][4])
{
  const int t = threadIdx.x, lane = t & 63, wave = t >> 6;
  const int wm = wave >> 1, wn = wave & 1;
  const int srow = lane >> 2;          // 0..15
  const int scol = (lane & 3) * 8;     // 0,8,16,24
  for (int k0 = 0; k0 < K; k0 += 32) {
    __syncthreads();
#pragma unroll
    for (int c = 0; c < 2; ++c) {
      const int row = c * 64 + wave * 16 + srow;
      const bf16* ga = A  + (size_t)(m0 + row) * K + k0 + scol;
      const bf16* gb = Bw + (size_t)(n0 + row) * K + k0 + scol;
      GLOAD_LDS16(ga, aT + c * 2048 + wave * 512);
      GLOAD_LDS16(gb, bT + c * 2048 + wave * 512);
    }
    __syncthreads();
    bf16x8 af[4], bfr[4];
#pragma unroll
    for (int i = 0; i < 4; ++i) {
      af[i]  = *(const bf16x8*)(aT + (wm * 64 + i * 16 + (lane & 15)) * 32 + (lane >> 4) * 8);
      bfr[i] = *(const bf16x8*)(bT + (wn * 64 + i * 16 + (lane & 15)) * 32 + (lane >> 4) * 8);
    }
#pragma unroll
    for (int i = 0; i < 4; ++i)
#pragma unroll
      for (int j = 0; j < 4; ++j)
        acc[i][j] = MFMA16(af[i], bfr[j], acc[i][j]);
  }
}

// ---------------- QKV projection + RoPE epilogue ----------------
__global__ __launch_bounds__(256) void proj_qkv(
    const bf16* __restrict__ xb,
    const bf16* __restrict__ wqb, const bf16* __restrict__ wkb, const bf16* __restrict__ wvb,
    bf16* __restrict__ Qb, bf16* __restrict__ Kb, bf16* __restrict__ Vb)
{
  __shared__ __align__(16) bf16 aT[4096];
  __shared__ __align__(16) bf16 bT[4096];
  const int z = blockIdx.z;
  const bf16* Ww = (z == 0) ? wqb : (z == 1) ? wkb : wvb;
  bf16*       Op = (z == 0) ? Qb  : (z == 1) ? Kb  : Vb;
  const int m0 = blockIdx.x * 128, n0 = blockIdx.y * 128;
  f32x4 acc[4][4] = {};
  gemm_core_128(xb, Ww, m0, n0, kD, aT, bT, acc);

  const int lane = threadIdx.x & 63, wave = threadIdx.x >> 6;
  const int wm = wave >> 1, wn = wave & 1, quad = lane >> 4, lc = lane & 15;
  const int hh = (n0 >> 6) + wn;     // head index; wave's 64-col span == one head
  if (z == 2) {                      // V: plain store
#pragma unroll
    for (int i = 0; i < 4; ++i)
#pragma unroll
      for (int r = 0; r < 4; ++r) {
        const int m = m0 + wm * 64 + i * 16 + quad * 4 + r;
        const int bidx = m >> 11, s = m & 2047;
        bf16* dst = Op + ((size_t)(bidx * kH + hh) * kS + s) * kHD;
#pragma unroll
        for (int j = 0; j < 4; ++j) dst[j * 16 + lc] = (bf16)acc[i][j][r];
      }
  } else {                           // Q/K: RoPE in-register (pair d with d+32)
#pragma unroll
    for (int j = 0; j < 2; ++j) {
      const int d = j * 16 + lc;     // 0..31
      const float invf = 1.0f / powf(10000.0f, (float)d * (1.0f / 32.0f));
#pragma unroll
      for (int i = 0; i < 4; ++i)
#pragma unroll
        for (int r = 0; r < 4; ++r) {
          const int m = m0 + wm * 64 + i * 16 + quad * 4 + r;
          const int bidx = m >> 11, s = m & 2047;
          float sn, cs;
          sincosf((float)s * invf, &sn, &cs);
          const float v0 = acc[i][j][r], v1 = acc[i][j + 2][r];
          bf16* dst = Op + ((size_t)(bidx * kH + hh) * kS + s) * kHD;
          dst[d]      = (bf16)(v0 * cs - v1 * sn);
          dst[d + 32] = (bf16)(v1 * cs + v0 * sn);
        }
    }
  }
}

// ---------------- flash attention (online softmax, MFMA) ----------------
__global__ __launch_bounds__(256) void attn(
    const bf16* __restrict__ Qb, const bf16* __restrict__ Kb,
    const bf16* __restrict__ Vb, bf16* __restrict__ Ob)
{
  __shared__ __align__(16) bf16 kT[64 * 72];      // [key][d], stride 72
  __shared__ __align__(16) bf16 vT[64 * 72];      // transposed: [d][key], stride 72
  __shared__ __align__(16) bf16 pT[4][32 * 72];   // per-wave P, [qrow][key], stride 72
  const int t = threadIdx.x, lane = t & 63, wave = t >> 6;
  const int quad = lane >> 4, lc = lane & 15;
  const int qt = blockIdx.x, bh = blockIdx.y;
  const size_t base = (size_t)bh * kS * kHD;
  const bf16* Qp = Qb + base + (size_t)qt * 128 * kHD;
  const bf16* Kp = Kb + base;
  const bf16* Vp = Vb + base;

  // Q fragments (A-layout), kept in registers for the whole kernel
  bf16x8 qf[2][2];
#pragma unroll
  for (int tm = 0; tm < 2; ++tm)
#pragma unroll
    for (int ks = 0; ks < 2; ++ks)
      qf[tm][ks] = *(const bf16x8*)(Qp + (wave * 32 + tm * 16 + lc) * kHD + ks * 32 + quad * 8);

  float mrow[2][4], lrow[2][4];
  f32x4 oacc[2][4] = {};
#pragma unroll
  for (int tm = 0; tm < 2; ++tm)
#pragma unroll
    for (int r = 0; r < 4; ++r) { mrow[tm][r] = -1e30f; lrow[tm][r] = 0.f; }

  const int srow_st = t >> 2;     // staging: row 0..63
  const int scb = t & 3;          // staging: 16-col block

  for (int kt = 0; kt < kS / 64; ++kt) {
    __syncthreads();
    {   // stage K tile (row-major, pad 72) and V tile (transposed, pad 72)
      const bf16* ksrc = Kp + (size_t)(kt * 64 + srow_st) * kHD + scb * 16;
      *(uint4*)&kT[srow_st * 72 + scb * 16]     = *(const uint4*)ksrc;
      *(uint4*)&kT[srow_st * 72 + scb * 16 + 8] = *(const uint4*)(ksrc + 8);
      const bf16* vsrc = Vp + (size_t)(kt * 64 + srow_st) * kHD + scb * 16;
      bf16 tmp[16];
      *(uint4*)&tmp[0] = *(const uint4*)vsrc;
      *(uint4*)&tmp[8] = *(const uint4*)(vsrc + 8);
#pragma unroll
      for (int e = 0; e < 16; ++e) vT[(scb * 16 + e) * 72 + srow_st] = tmp[e];
    }
    __syncthreads();

    // S = Q K^T (per wave: 32 q-rows x 64 keys)
    bf16x8 kf[4][2];
#pragma unroll
    for (int nk = 0; nk < 4; ++nk)
#pragma unroll
      for (int ks = 0; ks < 2; ++ks)
        kf[nk][ks] = *(const bf16x8*)&kT[(nk * 16 + lc) * 72 + ks * 32 + quad * 8];

    f32x4 sc[2][4] = {};
#pragma unroll
    for (int tm = 0; tm < 2; ++tm)
#pragma unroll
      for (int nk = 0; nk < 4; ++nk)
#pragma unroll
        for (int ks = 0; ks < 2; ++ks)
          sc[tm][nk] = MFMA16(qf[tm][ks], kf[nk][ks], sc[tm][nk]);

    // online softmax + write P (bf16) to per-wave LDS
    bf16* pw = &pT[wave][0];
#pragma unroll
    for (int tm = 0; tm < 2; ++tm)
#pragma unroll
      for (int r = 0; r < 4; ++r) {
        float mx = -1e30f;
#pragma unroll
        for (int nk = 0; nk < 4; ++nk) { sc[tm][nk][r] *= kScale; mx = fmaxf(mx, sc[tm][nk][r]); }
#pragma unroll
        for (int off = 1; off < 16; off <<= 1) mx = fmaxf(mx, __shfl_xor(mx, off, 64));
        const float mold = mrow[tm][r];
        const float mnew = fmaxf(mold, mx);
        const float alpha = __expf(mold - mnew);   // first iter: exp(-huge) = 0
        float rsum = 0.f;
#pragma unroll
        for (int nk = 0; nk < 4; ++nk) {
          const float p = __expf(sc[tm][nk][r] - mnew);
          sc[tm][nk][r] = p; rsum += p;
        }
#pragma unroll
        for (int off = 1; off < 16; off <<= 1) rsum += __shfl_xor(rsum, off, 64);
        mrow[tm][r] = mnew;
        lrow[tm][r] = lrow[tm][r] * alpha + rsum;
#pragma unroll
        for (int nd = 0; nd < 4; ++nd) oacc[tm][nd][r] *= alpha;
#pragma unroll
        for (int nk = 0; nk < 4; ++nk)
          pw[(tm * 16 + quad * 4 + r) * 72 + nk * 16 + lc] = (bf16)sc[tm][nk][r];
      }
    __syncthreads();   // make P visible (and ordered) for A-layout re-read

    // O += P V  (P via LDS round-trip C-layout -> A-layout)
    bf16x8 vf[4][2];
#pragma unroll
    for (int nd = 0; nd < 4; ++nd)
#pragma unroll
      for (int ks = 0; ks < 2; ++ks)
        vf[nd][ks] = *(const bf16x8*)&vT[(nd * 16 + lc) * 72 + ks * 32 + quad * 8];
#pragma unroll
    for (int tm = 0; tm < 2; ++tm) {
      bf16x8 pf[2];
#pragma unroll
      for (int ks = 0; ks < 2; ++ks)
        pf[ks] = *(const bf16x8*)&pw[(tm * 16 + lc) * 72 + ks * 32 + quad * 8];
#pragma unroll
      for (int nd = 0; nd < 4; ++nd)
#pragma unroll
        for (int ks = 0; ks < 2; ++ks)
          oacc[tm][nd] = MFMA16(pf[ks], vf[nd][ks], oacc[tm][nd]);
    }
  }

  // normalize + store O as bf16 in [B,S,D] layout for the output GEMM
  const int b = bh >> 4, h = bh & 15;
#pragma unroll
  for (int tm = 0; tm < 2; ++tm)
#pragma unroll
    for (int r = 0; r < 4; ++r) {
      const float inv = 1.0f / lrow[tm][r];
      const int s = qt * 128 + wave * 32 + tm * 16 + quad * 4 + r;
      bf16* dst = Ob + ((size_t)(b * kS + s)) * kD + h * kHD;
#pragma unroll
      for (int nd = 0; nd < 4; ++nd)
        dst[nd * 16 + lc] = (bf16)(oacc[tm][nd][r] * inv);
    }
}

// ---------------- output projection (fp32 epilogue) ----------------
__global__ __launch_bounds__(256) void out_proj(
    const bf16* __restrict__ Ab, const bf16* __restrict__ wob, float* __restrict__ Cout)
{
  __shared__ __align__(16) bf16 aT[4096];
  __shared__ __align__(16) bf16 bT[4096];
  const int m0 = blockIdx.x * 128, n0 = blockIdx.y * 128;
  f32x4 acc[4][4] = {};
  gemm_core_128(Ab, wob, m0, n0, kD, aT, bT, acc);
  const int lane = threadIdx.x & 63, wave = threadIdx.x >> 6;
  const int wm = wave >> 1, wn = wave & 1, quad = lane >> 4, lc = lane & 15;
#pragma unroll
  for (int i = 0; i < 4; ++i)
#pragma unroll
    for (int r = 0; r < 4; ++r) {
      const int m = m0 + wm * 64 + i * 16 + quad * 4 + r;
#pragma unroll
      for (int j = 0; j < 4; ++j)
        Cout[(size_t)m * kD + n0 + wn * 64 + j * 16 + lc] = acc[i][j][r];
    }
}

extern "C" void kernel_launch(void* const* d_in, const int* in_sizes, int n_in,
                              void* d_out, int out_size, void* d_ws, size_t ws_size,
                              hipStream_t stream)
{
  const float* x  = (const float*)d_in[0];
  const float* wq = (const float*)d_in[1];
  const float* wk = (const float*)d_in[2];
  const float* wv = (const float*)d_in[3];
  const float* wo = (const float*)d_in[4];
  float* out = (float*)d_out;

  char* ws = (char*)d_ws;
  const size_t MB = 1024 * 1024;
  if (ws_size < 48 * MB) return;   // clean failure signal if scratch too small
  bf16* xb  = (bf16*)(ws + 0 * MB);   // 8 MB
  bf16* wqb = (bf16*)(ws + 8 * MB);   // 2 MB each
  bf16* wkb = (bf16*)(ws + 10 * MB);
  bf16* wvb = (bf16*)(ws + 12 * MB);
  bf16* wob = (bf16*)(ws + 14 * MB);
  bf16* Qb  = (bf16*)(ws + 16 * MB);  // 8 MB each, [B*H][S][64]
  bf16* Kb  = (bf16*)(ws + 24 * MB);
  bf16* Vb  = (bf16*)(ws + 32 * MB);
  bf16* Ob  = (bf16*)(ws + 40 * MB);  // 8 MB, [B,S,D]

  cvt_all<<<8192, 256, 0, stream>>>(x, wq, wk, wv, wo, xb, wqb, wkb, wvb, wob);
  proj_qkv<<<dim3(32, 8, 3), 256, 0, stream>>>(xb, wqb, wkb, wvb, Qb, Kb, Vb);
  attn<<<dim3(16, 32), 256, 0, stream>>>(Qb, Kb, Vb, Ob);
  out_proj<<<dim3(32, 8), 256, 0, stream>>>(Ob, wob, out);
}

// Round 2
// 215.828 us; speedup vs baseline: 1.3871x; 1.3871x over previous
//
#include <hip/hip_runtime.h>
#include <hip/hip_bf16.h>
#include <math.h>
#include <stdint.h>

typedef __bf16 bf16;
typedef __bf16 bf16x8 __attribute__((ext_vector_type(8)));
typedef __bf16 bf16x4 __attribute__((ext_vector_type(4)));
typedef float  f32x4  __attribute__((ext_vector_type(4)));

#define MFMA16(a,b,c) __builtin_amdgcn_mfma_f32_16x16x32_bf16((a),(b),(c),0,0,0)
#define GLOAD_LDS16(g, l) \
  __builtin_amdgcn_global_load_lds((__attribute__((address_space(1))) void*)(g), \
                                   (__attribute__((address_space(3))) void*)(l), 16, 0, 0)

static constexpr int kB  = 2;
static constexpr int kS  = 2048;
static constexpr int kD  = 1024;
static constexpr int kH  = 16;
static constexpr int kHD = 64;
static constexpr int kM  = kB * kS;         // 4096
// exp(s*0.125) = exp2(s * 0.125 * log2(e))
static constexpr float kExpC = 0.125f * 1.44269504f;

// ---------------- fp32 -> bf16 conversion (x + 4 weights) + RoPE table ----------------
__global__ void cvt_all(const float* __restrict__ x,
                        const float* __restrict__ wq, const float* __restrict__ wk,
                        const float* __restrict__ wv, const float* __restrict__ wo,
                        bf16* __restrict__ xb,
                        bf16* __restrict__ wqb, bf16* __restrict__ wkb,
                        bf16* __restrict__ wvb, bf16* __restrict__ wob,
                        float2* __restrict__ rtab)
{
  const int i = blockIdx.x * 256 + threadIdx.x;   // float4 index
  const int NX4 = (kM * kD) / 4;                  // 1048576
  const int NW4 = (kD * kD) / 4;                  // 262144 = 2^18
  if (i >= NX4 + 4 * NW4) {                       // RoPE cos/sin table: 2048 x 32
    const int idx = i - (NX4 + 4 * NW4);          // exactly 65536 of these
    const int s = idx >> 5, d = idx & 31;
    const float f = exp2f(-(float)d * 0.4152410118609203f);  // 10000^(-d/32)
    float sn, cs;
    sincosf((float)s * f, &sn, &cs);
    rtab[idx] = make_float2(cs, sn);
    return;
  }
  const float* src; bf16* dst; int off;
  if (i < NX4) { src = x; dst = xb; off = i; }
  else {
    const int j = i - NX4;
    const int seg = j >> 18;
    off = j & (NW4 - 1);
    src = (seg == 0) ? wq : (seg == 1) ? wk : (seg == 2) ? wv : wo;
    dst = (seg == 0) ? wqb : (seg == 1) ? wkb : (seg == 2) ? wvb : wob;
  }
  const float4 v = ((const float4*)src)[off];
  bf16x4 o = { (bf16)v.x, (bf16)v.y, (bf16)v.z, (bf16)v.w };
  ((bf16x4*)dst)[off] = o;
}

// ---------------- 128x128 tile bf16 GEMM core (C = A * B^T) ----------------
__device__ __forceinline__ void gemm_core_128(
    const bf16* __restrict__ A, const bf16* __restrict__ Bw,
    int m0, int n0, int K, bf16* aT, bf16* bT, f32x4 acc[4][4])
{
  const int t = threadIdx.x, lane = t & 63, wave = t >> 6;
  const int wm = wave >> 1, wn = wave & 1;
  const int srow = lane >> 2;          // 0..15
  const int scol = (lane & 3) * 8;     // 0,8,16,24
  for (int k0 = 0; k0 < K; k0 += 32) {
    __syncthreads();
#pragma unroll
    for (int c = 0; c < 2; ++c) {
      const int row = c * 64 + wave * 16 + srow;
      const bf16* ga = A  + (size_t)(m0 + row) * K + k0 + scol;
      const bf16* gb = Bw + (size_t)(n0 + row) * K + k0 + scol;
      GLOAD_LDS16(ga, aT + c * 2048 + wave * 512);
      GLOAD_LDS16(gb, bT + c * 2048 + wave * 512);
    }
    __syncthreads();
    bf16x8 af[4], bfr[4];
#pragma unroll
    for (int i = 0; i < 4; ++i) {
      af[i]  = *(const bf16x8*)(aT + (wm * 64 + i * 16 + (lane & 15)) * 32 + (lane >> 4) * 8);
      bfr[i] = *(const bf16x8*)(bT + (wn * 64 + i * 16 + (lane & 15)) * 32 + (lane >> 4) * 8);
    }
#pragma unroll
    for (int i = 0; i < 4; ++i)
#pragma unroll
      for (int j = 0; j < 4; ++j)
        acc[i][j] = MFMA16(af[i], bfr[j], acc[i][j]);
  }
}

// ---------------- QKV projection + RoPE epilogue (table) ----------------
__global__ __launch_bounds__(256) void proj_qkv(
    const bf16* __restrict__ xb,
    const bf16* __restrict__ wqb, const bf16* __restrict__ wkb, const bf16* __restrict__ wvb,
    bf16* __restrict__ Qb, bf16* __restrict__ Kb, bf16* __restrict__ Vb,
    const float2* __restrict__ rtab)
{
  __shared__ __align__(16) bf16 aT[4096];
  __shared__ __align__(16) bf16 bT[4096];
  const int z = blockIdx.z;
  const bf16* Ww = (z == 0) ? wqb : (z == 1) ? wkb : wvb;
  bf16*       Op = (z == 0) ? Qb  : (z == 1) ? Kb  : Vb;
  const int m0 = blockIdx.x * 128, n0 = blockIdx.y * 128;
  f32x4 acc[4][4] = {};
  gemm_core_128(xb, Ww, m0, n0, kD, aT, bT, acc);

  const int lane = threadIdx.x & 63, wave = threadIdx.x >> 6;
  const int wm = wave >> 1, wn = wave & 1, quad = lane >> 4, lc = lane & 15;
  const int hh = (n0 >> 6) + wn;     // head index; wave's 64-col span == one head
  if (z == 2) {                      // V: plain store
#pragma unroll
    for (int i = 0; i < 4; ++i)
#pragma unroll
      for (int r = 0; r < 4; ++r) {
        const int m = m0 + wm * 64 + i * 16 + quad * 4 + r;
        const int bidx = m >> 11, s = m & 2047;
        bf16* dst = Op + ((size_t)(bidx * kH + hh) * kS + s) * kHD;
#pragma unroll
        for (int j = 0; j < 4; ++j) dst[j * 16 + lc] = (bf16)acc[i][j][r];
      }
  } else {                           // Q/K: RoPE in-register (pair d with d+32)
#pragma unroll
    for (int j = 0; j < 2; ++j) {
      const int d = j * 16 + lc;     // 0..31
#pragma unroll
      for (int i = 0; i < 4; ++i)
#pragma unroll
        for (int r = 0; r < 4; ++r) {
          const int m = m0 + wm * 64 + i * 16 + quad * 4 + r;
          const int bidx = m >> 11, s = m & 2047;
          const float2 cs = rtab[s * 32 + d];
          const float v0 = acc[i][j][r], v1 = acc[i][j + 2][r];
          bf16* dst = Op + ((size_t)(bidx * kH + hh) * kS + s) * kHD;
          dst[d]      = (bf16)(v0 * cs.x - v1 * cs.y);
          dst[d + 32] = (bf16)(v1 * cs.x + v0 * cs.y);
        }
    }
  }
}

// ---------------- flash attention, max-free softmax, 128-key tiles ----------------
__global__ __launch_bounds__(256, 2) void attn(
    const bf16* __restrict__ Qb, const bf16* __restrict__ Kb,
    const bf16* __restrict__ Vb, bf16* __restrict__ Ob)
{
  __shared__ __align__(16) bf16 kT[128 * 72];     // [key][d], stride 72
  __shared__ __align__(16) bf16 vT[64 * 136];     // transposed: [d][key], stride 136
  __shared__ __align__(16) bf16 pT[4][32 * 136];  // per-wave P, [qrow][key], stride 136
  const int t = threadIdx.x, lane = t & 63, wave = t >> 6;
  const int quad = lane >> 4, lc = lane & 15;
  const int qt = blockIdx.x, bh = blockIdx.y;
  const size_t base = (size_t)bh * kS * kHD;
  const bf16* Qp = Qb + base + (size_t)qt * 128 * kHD;
  const bf16* Kp = Kb + base;
  const bf16* Vp = Vb + base;

  // Q fragments (A-layout), in registers for the whole kernel
  bf16x8 qf[2][2];
#pragma unroll
  for (int tm = 0; tm < 2; ++tm)
#pragma unroll
    for (int ks = 0; ks < 2; ++ks)
      qf[tm][ks] = *(const bf16x8*)(Qp + (wave * 32 + tm * 16 + lc) * kHD + ks * 32 + quad * 8);

  f32x4 oacc[2][4] = {};
  f32x4 lacc[2] = {};
  const bf16 one = (bf16)1.0f;
  const bf16x8 ones = { one, one, one, one, one, one, one, one };

  // staging assignment: 2 threads per row (key); each does 64 B
  const int srow = t >> 1;            // 0..127
  const int shalf = (t & 1) * 32;     // d-offset 0 or 32

  for (int kt = 0; kt < kS / 128; ++kt) {
    __syncthreads();
    {   // K tile: [key][d] row-major, stride 72 (conflict-free b128 rows)
      const bf16* ksrc = Kp + (size_t)(kt * 128 + srow) * kHD + shalf;
#pragma unroll
      for (int u = 0; u < 4; ++u)
        *(uint4*)&kT[srow * 72 + shalf + u * 8] = *(const uint4*)(ksrc + u * 8);
      // V tile transposed: [d][key], stride 136; writes are key-contiguous -> 2-way max
      const bf16* vsrc = Vp + (size_t)(kt * 128 + srow) * kHD + shalf;
      bf16 tmp[32];
#pragma unroll
      for (int u = 0; u < 4; ++u)
        *(uint4*)&tmp[u * 8] = *(const uint4*)(vsrc + u * 8);
#pragma unroll
      for (int e = 0; e < 32; ++e)
        vT[(shalf + e) * 136 + srow] = tmp[e];
    }
    __syncthreads();

    // S = Q K^T : per wave 32 q-rows x 128 keys
    f32x4 sc[2][8] = {};
#pragma unroll
    for (int nk = 0; nk < 8; ++nk) {
      const bf16x8 kf0 = *(const bf16x8*)&kT[(nk * 16 + lc) * 72 + quad * 8];
      const bf16x8 kf1 = *(const bf16x8*)&kT[(nk * 16 + lc) * 72 + 32 + quad * 8];
#pragma unroll
      for (int tm = 0; tm < 2; ++tm) {
        sc[tm][nk] = MFMA16(qf[tm][0], kf0, sc[tm][nk]);
        sc[tm][nk] = MFMA16(qf[tm][1], kf1, sc[tm][nk]);
      }
    }

    // max-free softmax: p = exp2(s * c); write P to per-wave LDS (no barrier needed)
    bf16* pw = &pT[wave][0];
#pragma unroll
    for (int tm = 0; tm < 2; ++tm)
#pragma unroll
      for (int nk = 0; nk < 8; ++nk)
#pragma unroll
        for (int r = 0; r < 4; ++r) {
          const float p = __builtin_amdgcn_exp2f(sc[tm][nk][r] * kExpC);
          pw[(tm * 16 + quad * 4 + r) * 136 + nk * 16 + lc] = (bf16)p;
        }

    // O += P V ; row sums via ones-MFMA (no shuffles)
    bf16x8 pf[2][4];
#pragma unroll
    for (int tm = 0; tm < 2; ++tm)
#pragma unroll
      for (int ks = 0; ks < 4; ++ks)
        pf[tm][ks] = *(const bf16x8*)&pw[(tm * 16 + lc) * 136 + ks * 32 + quad * 8];
#pragma unroll
    for (int ks = 0; ks < 4; ++ks)
#pragma unroll
      for (int tm = 0; tm < 2; ++tm)
        lacc[tm] = MFMA16(pf[tm][ks], ones, lacc[tm]);
#pragma unroll
    for (int nd = 0; nd < 4; ++nd)
#pragma unroll
      for (int ks = 0; ks < 4; ++ks) {
        const bf16x8 vf = *(const bf16x8*)&vT[(nd * 16 + lc) * 136 + ks * 32 + quad * 8];
#pragma unroll
        for (int tm = 0; tm < 2; ++tm)
          oacc[tm][nd] = MFMA16(pf[tm][ks], vf, oacc[tm][nd]);
      }
  }

  // normalize + store O as bf16 in [B,S,D] layout for the output GEMM
  const int b = bh >> 4, h = bh & 15;
#pragma unroll
  for (int tm = 0; tm < 2; ++tm)
#pragma unroll
    for (int r = 0; r < 4; ++r) {
      const float inv = 1.0f / lacc[tm][r];
      const int s = qt * 128 + wave * 32 + tm * 16 + quad * 4 + r;
      bf16* dst = Ob + ((size_t)(b * kS + s)) * kD + h * kHD;
#pragma unroll
      for (int nd = 0; nd < 4; ++nd)
        dst[nd * 16 + lc] = (bf16)(oacc[tm][nd][r] * inv);
    }
}

// ---------------- output projection (fp32 epilogue) ----------------
__global__ __launch_bounds__(256) void out_proj(
    const bf16* __restrict__ Ab, const bf16* __restrict__ wob, float* __restrict__ Cout)
{
  __shared__ __align__(16) bf16 aT[4096];
  __shared__ __align__(16) bf16 bT[4096];
  const int m0 = blockIdx.x * 128, n0 = blockIdx.y * 128;
  f32x4 acc[4][4] = {};
  gemm_core_128(Ab, wob, m0, n0, kD, aT, bT, acc);
  const int lane = threadIdx.x & 63, wave = threadIdx.x >> 6;
  const int wm = wave >> 1, wn = wave & 1, quad = lane >> 4, lc = lane & 15;
#pragma unroll
  for (int i = 0; i < 4; ++i)
#pragma unroll
    for (int r = 0; r < 4; ++r) {
      const int m = m0 + wm * 64 + i * 16 + quad * 4 + r;
#pragma unroll
      for (int j = 0; j < 4; ++j)
        Cout[(size_t)m * kD + n0 + wn * 64 + j * 16 + lc] = acc[i][j][r];
    }
}

extern "C" void kernel_launch(void* const* d_in, const int* in_sizes, int n_in,
                              void* d_out, int out_size, void* d_ws, size_t ws_size,
                              hipStream_t stream)
{
  const float* x  = (const float*)d_in[0];
  const float* wq = (const float*)d_in[1];
  const float* wk = (const float*)d_in[2];
  const float* wv = (const float*)d_in[3];
  const float* wo = (const float*)d_in[4];
  float* out = (float*)d_out;

  char* ws = (char*)d_ws;
  const size_t MB = 1024 * 1024;
  if (ws_size < 49 * MB) return;
  bf16* xb  = (bf16*)(ws + 0 * MB);   // 8 MB
  bf16* wqb = (bf16*)(ws + 8 * MB);   // 2 MB each
  bf16* wkb = (bf16*)(ws + 10 * MB);
  bf16* wvb = (bf16*)(ws + 12 * MB);
  bf16* wob = (bf16*)(ws + 14 * MB);
  bf16* Qb  = (bf16*)(ws + 16 * MB);  // 8 MB each, [B*H][S][64]
  bf16* Kb  = (bf16*)(ws + 24 * MB);
  bf16* Vb  = (bf16*)(ws + 32 * MB);
  bf16* Ob  = (bf16*)(ws + 40 * MB);  // 8 MB, [B,S,D]
  float2* rtab = (float2*)(ws + 48 * MB);  // 512 KB RoPE table

  cvt_all<<<8448, 256, 0, stream>>>(x, wq, wk, wv, wo, xb, wqb, wkb, wvb, wob, rtab);
  proj_qkv<<<dim3(32, 8, 3), 256, 0, stream>>>(xb, wqb, wkb, wvb, Qb, Kb, Vb, rtab);
  attn<<<dim3(16, 32), 256, 0, stream>>>(Qb, Kb, Vb, Ob);
  out_proj<<<dim3(32, 8), 256, 0, stream>>>(Ob, wob, out);
}

// Round 5
// 207.438 us; speedup vs baseline: 1.4432x; 1.0404x over previous
//
#include <hip/hip_runtime.h>
#include <hip/hip_bf16.h>
#include <math.h>
#include <stdint.h>

typedef __bf16 bf16;
typedef __bf16 bf16x8 __attribute__((ext_vector_type(8)));
typedef __bf16 bf16x4 __attribute__((ext_vector_type(4)));
typedef float  f32x4  __attribute__((ext_vector_type(4)));

#define MFMA16(a,b,c) __builtin_amdgcn_mfma_f32_16x16x32_bf16((a),(b),(c),0,0,0)
#define GLOAD_LDS16(g, l) \
  __builtin_amdgcn_global_load_lds((__attribute__((address_space(1))) void*)(g), \
                                   (__attribute__((address_space(3))) void*)(l), 16, 0, 0)

static constexpr int kB  = 2;
static constexpr int kS  = 2048;
static constexpr int kD  = 1024;
static constexpr int kH  = 16;
static constexpr int kHD = 64;
static constexpr int kM  = kB * kS;         // 4096
// exp(s*0.125) = exp2(s * 0.125 * log2(e)) ; folded into Q at proj epilogue
static constexpr float kExpC = 0.125f * 1.44269504f;

// ---------------- fp32 -> bf16 conversion (x + 4 weights) + RoPE table ----------------
__global__ void cvt_all(const float* __restrict__ x,
                        const float* __restrict__ wq, const float* __restrict__ wk,
                        const float* __restrict__ wv, const float* __restrict__ wo,
                        bf16* __restrict__ xb,
                        bf16* __restrict__ wqb, bf16* __restrict__ wkb,
                        bf16* __restrict__ wvb, bf16* __restrict__ wob,
                        float2* __restrict__ rtab)
{
  const int i = blockIdx.x * 256 + threadIdx.x;   // float4 index
  const int NX4 = (kM * kD) / 4;                  // 1048576
  const int NW4 = (kD * kD) / 4;                  // 262144 = 2^18
  if (i >= NX4 + 4 * NW4) {                       // RoPE cos/sin table: 2048 x 32
    const int idx = i - (NX4 + 4 * NW4);          // exactly 65536 of these
    const int s = idx >> 5, d = idx & 31;
    const float f = exp2f(-(float)d * 0.4152410118609203f);  // 10000^(-d/32)
    float sn, cs;
    sincosf((float)s * f, &sn, &cs);
    rtab[idx] = make_float2(cs, sn);
    return;
  }
  const float* src; bf16* dst; int off;
  if (i < NX4) { src = x; dst = xb; off = i; }
  else {
    const int j = i - NX4;
    const int seg = j >> 18;
    off = j & (NW4 - 1);
    src = (seg == 0) ? wq : (seg == 1) ? wk : (seg == 2) ? wv : wo;
    dst = (seg == 0) ? wqb : (seg == 1) ? wkb : (seg == 2) ? wvb : wob;
  }
  const float4 v = ((const float4*)src)[off];
  bf16x4 o = { (bf16)v.x, (bf16)v.y, (bf16)v.z, (bf16)v.w };
  ((bf16x4*)dst)[off] = o;
}

// ---------------- 128x128 tile bf16 GEMM core (C = A * B^T) ----------------
__device__ __forceinline__ void gemm_core_128(
    const bf16* __restrict__ A, const bf16* __restrict__ Bw,
    int m0, int n0, int K, bf16* aT, bf16* bT, f32x4 acc[4][4])
{
  const int t = threadIdx.x, lane = t & 63, wave = t >> 6;
  const int wm = wave >> 1, wn = wave & 1;
  const int srow = lane >> 2;          // 0..15
  const int scol = (lane & 3) * 8;     // 0,8,16,24
  for (int k0 = 0; k0 < K; k0 += 32) {
    __syncthreads();
#pragma unroll
    for (int c = 0; c < 2; ++c) {
      const int row = c * 64 + wave * 16 + srow;
      const bf16* ga = A  + (size_t)(m0 + row) * K + k0 + scol;
      const bf16* gb = Bw + (size_t)(n0 + row) * K + k0 + scol;
      GLOAD_LDS16(ga, aT + c * 2048 + wave * 512);
      GLOAD_LDS16(gb, bT + c * 2048 + wave * 512);
    }
    __syncthreads();
    bf16x8 af[4], bfr[4];
#pragma unroll
    for (int i = 0; i < 4; ++i) {
      af[i]  = *(const bf16x8*)(aT + (wm * 64 + i * 16 + (lane & 15)) * 32 + (lane >> 4) * 8);
      bfr[i] = *(const bf16x8*)(bT + (wn * 64 + i * 16 + (lane & 15)) * 32 + (lane >> 4) * 8);
    }
#pragma unroll
    for (int i = 0; i < 4; ++i)
#pragma unroll
      for (int j = 0; j < 4; ++j)
        acc[i][j] = MFMA16(af[i], bfr[j], acc[i][j]);
  }
}

// ---------------- QKV projection + RoPE epilogue (table; Q pre-scaled) ----------------
__global__ __launch_bounds__(256) void proj_qkv(
    const bf16* __restrict__ xb,
    const bf16* __restrict__ wqb, const bf16* __restrict__ wkb, const bf16* __restrict__ wvb,
    bf16* __restrict__ Qb, bf16* __restrict__ Kb, bf16* __restrict__ Vb,
    const float2* __restrict__ rtab)
{
  __shared__ __align__(16) bf16 aT[4096];
  __shared__ __align__(16) bf16 bT[4096];
  const int z = blockIdx.z;
  const bf16* Ww = (z == 0) ? wqb : (z == 1) ? wkb : wvb;
  bf16*       Op = (z == 0) ? Qb  : (z == 1) ? Kb  : Vb;
  const int m0 = blockIdx.x * 128, n0 = blockIdx.y * 128;
  f32x4 acc[4][4] = {};
  gemm_core_128(xb, Ww, m0, n0, kD, aT, bT, acc);

  const int lane = threadIdx.x & 63, wave = threadIdx.x >> 6;
  const int wm = wave >> 1, wn = wave & 1, quad = lane >> 4, lc = lane & 15;
  const int hh = (n0 >> 6) + wn;     // head index; wave's 64-col span == one head
  if (z == 2) {                      // V: plain store
#pragma unroll
    for (int i = 0; i < 4; ++i)
#pragma unroll
      for (int r = 0; r < 4; ++r) {
        const int m = m0 + wm * 64 + i * 16 + quad * 4 + r;
        const int bidx = m >> 11, s = m & 2047;
        bf16* dst = Op + ((size_t)(bidx * kH + hh) * kS + s) * kHD;
#pragma unroll
        for (int j = 0; j < 4; ++j) dst[j * 16 + lc] = (bf16)acc[i][j][r];
      }
  } else {                           // Q/K: RoPE in-register (pair d with d+32)
    const float f = (z == 0) ? kExpC : 1.0f;   // fold softmax scale into Q
#pragma unroll
    for (int j = 0; j < 2; ++j) {
      const int d = j * 16 + lc;     // 0..31
#pragma unroll
      for (int i = 0; i < 4; ++i)
#pragma unroll
        for (int r = 0; r < 4; ++r) {
          const int m = m0 + wm * 64 + i * 16 + quad * 4 + r;
          const int bidx = m >> 11, s = m & 2047;
          const float2 cs = rtab[s * 32 + d];
          const float v0 = acc[i][j][r], v1 = acc[i][j + 2][r];
          bf16* dst = Op + ((size_t)(bidx * kH + hh) * kS + s) * kHD;
          dst[d]      = (bf16)((v0 * cs.x - v1 * cs.y) * f);
          dst[d + 32] = (bf16)((v1 * cs.x + v0 * cs.y) * f);
        }
    }
  }
}

// ---------------- V transpose: Vb[bh][s][d] -> Vt[bh][d][s] (once) ----------------
__global__ __launch_bounds__(256) void transpose_v(
    const bf16* __restrict__ Vb, bf16* __restrict__ Vt)
{
  __shared__ __align__(16) bf16 buf[128 * 72];
  const int t = threadIdx.x;
  const int kc = blockIdx.x, bh = blockIdx.y;    // 128-key chunk, head
  const bf16* src = Vb + ((size_t)bh * kS + kc * 128) * kHD;
  {
    const int srow = t >> 1, half = (t & 1) * 32;
#pragma unroll
    for (int u = 0; u < 4; ++u)
      *(uint4*)&buf[srow * 72 + half + u * 8] = *(const uint4*)(src + srow * kHD + half + u * 8);
  }
  __syncthreads();
  {
    const int d = t & 63, c = t >> 6;            // c = wave
    bf16 tmp[32];
#pragma unroll
    for (int e = 0; e < 32; ++e) tmp[e] = buf[(c * 32 + e) * 72 + d];
    bf16* dst = Vt + ((size_t)bh * kHD + d) * kS + kc * 128 + c * 32;
#pragma unroll
    for (int u = 0; u < 4; ++u)
      *(uint4*)(dst + u * 8) = *(const uint4*)&tmp[u * 8];
  }
}

// ---------------- flash attention: S^T trick, packed P writes ----------------
// LDS: kT [key=128][d=64] stride 72; vT [d=64][key=128] stride 136;
//      pT per-wave [q=32][key=128] stride 136. Total 70656 B -> 2 blocks/CU.
__global__ __launch_bounds__(256, 2) void attn(
    const bf16* __restrict__ Qb, const bf16* __restrict__ Kb,
    const bf16* __restrict__ Vt, bf16* __restrict__ Ob)
{
  __shared__ __align__(16) bf16 kT[128 * 72];
  __shared__ __align__(16) bf16 vT[64 * 136];
  __shared__ __align__(16) bf16 pT[4][32 * 136];
  const int t = threadIdx.x, lane = t & 63, wave = t >> 6;
  const int quad = lane >> 4, lc = lane & 15;
  const int qt = blockIdx.x, bh = blockIdx.y;
  const size_t base = (size_t)bh * kS * kHD;
  const bf16* Qp = Qb + base + (size_t)qt * 128 * kHD;
  const bf16* Kp = Kb + base;
  const bf16* Vp = Vt + base;                     // [d][s]

  // Q fragments (B-operand layout = same as A), in registers for the whole kernel
  bf16x8 qf[2][2];
#pragma unroll
  for (int tm = 0; tm < 2; ++tm)
#pragma unroll
    for (int ks = 0; ks < 2; ++ks)
      qf[tm][ks] = *(const bf16x8*)(Qp + (wave * 32 + tm * 16 + lc) * kHD + ks * 32 + quad * 8);

  f32x4 oacc[2][4] = {};
  f32x4 lacc[2] = {};
  const bf16 one = (bf16)1.0f;
  const bf16x8 ones = { one, one, one, one, one, one, one, one };

  // staging: K: 2 threads/row, 64 B each. V^T: thread (d=t>>2, c=t&3), 64 B each.
  const int srow = t >> 1, shalf = (t & 1) * 32;
  const int vd = t >> 2, vc = t & 3;

  for (int kt = 0; kt < kS / 128; ++kt) {
    __syncthreads();
    {
      const bf16* ksrc = Kp + (size_t)(kt * 128 + srow) * kHD + shalf;
#pragma unroll
      for (int u = 0; u < 4; ++u)
        *(uint4*)&kT[srow * 72 + shalf + u * 8] = *(const uint4*)(ksrc + u * 8);
      const bf16* vsrc = Vp + (size_t)vd * kS + kt * 128 + vc * 32;
#pragma unroll
      for (int u = 0; u < 4; ++u)
        *(uint4*)&vT[vd * 136 + vc * 32 + u * 8] = *(const uint4*)(vsrc + u * 8);
    }
    __syncthreads();

    // S^T = K Q^T : acc element (key = nk*16 + quad*4 + r, q = tm*16 + lc)
    f32x4 sc[2][8] = {};
#pragma unroll
    for (int nk = 0; nk < 8; ++nk) {
      const bf16x8 kf0 = *(const bf16x8*)&kT[(nk * 16 + lc) * 72 + quad * 8];
      const bf16x8 kf1 = *(const bf16x8*)&kT[(nk * 16 + lc) * 72 + 32 + quad * 8];
#pragma unroll
      for (int tm = 0; tm < 2; ++tm) {
        sc[tm][nk] = MFMA16(kf0, qf[tm][0], sc[tm][nk]);
        sc[tm][nk] = MFMA16(kf1, qf[tm][1], sc[tm][nk]);
      }
    }

    // p = exp2(s) (scale pre-folded into Q); 4 consecutive keys -> packed b64 store
    bf16* pw = &pT[wave][0];
#pragma unroll
    for (int tm = 0; tm < 2; ++tm)
#pragma unroll
      for (int nk = 0; nk < 8; ++nk) {
        bf16x4 p;
#pragma unroll
        for (int r = 0; r < 4; ++r)
          p[r] = (bf16)__builtin_amdgcn_exp2f(sc[tm][nk][r]);
        *(bf16x4*)&pw[(tm * 16 + lc) * 136 + nk * 16 + quad * 4] = p;
      }

    // O += P V ; row sums via ones-MFMA (no barrier: pT is per-wave)
    bf16x8 pf[2][4];
#pragma unroll
    for (int tm = 0; tm < 2; ++tm)
#pragma unroll
      for (int ks = 0; ks < 4; ++ks)
        pf[tm][ks] = *(const bf16x8*)&pw[(tm * 16 + lc) * 136 + ks * 32 + quad * 8];
#pragma unroll
    for (int ks = 0; ks < 4; ++ks)
#pragma unroll
      for (int tm = 0; tm < 2; ++tm)
        lacc[tm] = MFMA16(pf[tm][ks], ones, lacc[tm]);
#pragma unroll
    for (int nd = 0; nd < 4; ++nd)
#pragma unroll
      for (int ks = 0; ks < 4; ++ks) {
        const bf16x8 vf = *(const bf16x8*)&vT[(nd * 16 + lc) * 136 + ks * 32 + quad * 8];
#pragma unroll
        for (int tm = 0; tm < 2; ++tm)
          oacc[tm][nd] = MFMA16(pf[tm][ks], vf, oacc[tm][nd]);
      }
  }

  // normalize + store O as bf16 in [B,S,D] layout for the output GEMM
  const int b = bh >> 4, h = bh & 15;
#pragma unroll
  for (int tm = 0; tm < 2; ++tm)
#pragma unroll
    for (int r = 0; r < 4; ++r) {
      const float inv = 1.0f / lacc[tm][r];
      const int s = qt * 128 + wave * 32 + tm * 16 + quad * 4 + r;
      bf16* dst = Ob + ((size_t)(b * kS + s)) * kD + h * kHD;
#pragma unroll
      for (int nd = 0; nd < 4; ++nd)
        dst[nd * 16 + lc] = (bf16)(oacc[tm][nd][r] * inv);
    }
}

// ---------------- output projection (fp32 epilogue) ----------------
__global__ __launch_bounds__(256) void out_proj(
    const bf16* __restrict__ Ab, const bf16* __restrict__ wob, float* __restrict__ Cout)
{
  __shared__ __align__(16) bf16 aT[4096];
  __shared__ __align__(16) bf16 bT[4096];
  const int m0 = blockIdx.x * 128, n0 = blockIdx.y * 128;
  f32x4 acc[4][4] = {};
  gemm_core_128(Ab, wob, m0, n0, kD, aT, bT, acc);
  const int lane = threadIdx.x & 63, wave = threadIdx.x >> 6;
  const int wm = wave >> 1, wn = wave & 1, quad = lane >> 4, lc = lane & 15;
#pragma unroll
  for (int i = 0; i < 4; ++i)
#pragma unroll
    for (int r = 0; r < 4; ++r) {
      const int m = m0 + wm * 64 + i * 16 + quad * 4 + r;
#pragma unroll
      for (int j = 0; j < 4; ++j)
        Cout[(size_t)m * kD + n0 + wn * 64 + j * 16 + lc] = acc[i][j][r];
    }
}

extern "C" void kernel_launch(void* const* d_in, const int* in_sizes, int n_in,
                              void* d_out, int out_size, void* d_ws, size_t ws_size,
                              hipStream_t stream)
{
  const float* x  = (const float*)d_in[0];
  const float* wq = (const float*)d_in[1];
  const float* wk = (const float*)d_in[2];
  const float* wv = (const float*)d_in[3];
  const float* wo = (const float*)d_in[4];
  float* out = (float*)d_out;

  char* ws = (char*)d_ws;
  const size_t MB = 1024 * 1024;
  if (ws_size < 57 * MB) return;
  bf16* xb  = (bf16*)(ws + 0 * MB);   // 8 MB
  bf16* wqb = (bf16*)(ws + 8 * MB);   // 2 MB each
  bf16* wkb = (bf16*)(ws + 10 * MB);
  bf16* wvb = (bf16*)(ws + 12 * MB);
  bf16* wob = (bf16*)(ws + 14 * MB);
  bf16* Qb  = (bf16*)(ws + 16 * MB);  // 8 MB each, [B*H][S][64]
  bf16* Kb  = (bf16*)(ws + 24 * MB);
  bf16* Vb  = (bf16*)(ws + 32 * MB);
  bf16* Ob  = (bf16*)(ws + 40 * MB);  // 8 MB, [B,S,D]
  float2* rtab = (float2*)(ws + 48 * MB);  // 512 KB RoPE table
  bf16* Vtp = (bf16*)(ws + 49 * MB);  // 8 MB, V transposed [B*H][64][S]

  cvt_all<<<8448, 256, 0, stream>>>(x, wq, wk, wv, wo, xb, wqb, wkb, wvb, wob, rtab);
  proj_qkv<<<dim3(32, 8, 3), 256, 0, stream>>>(xb, wqb, wkb, wvb, Qb, Kb, Vb, rtab);
  transpose_v<<<dim3(16, 32), 256, 0, stream>>>(Vb, Vtp);
  attn<<<dim3(16, 32), 256, 0, stream>>>(Qb, Kb, Vtp, Ob);
  out_proj<<<dim3(32, 8), 256, 0, stream>>>(Ob, wob, out);
}